// Round 1
// 126.506 us; speedup vs baseline: 1.0518x; 1.0518x over previous
//
#include <hip/hip_runtime.h>

#define L_IN   32768
#define L_OUT  32766          // (32768 - 3) + 1
#define C_IN   32
#define C_OUT  32
#define KW     3
#define TILE_L 128            // output positions per block
#define NTILES 256            // 32768 / 128
#define PITCH  40             // ushorts per transposed row: 32 ci + 8 pad = 80 B
#define XROWS  (TILE_L + 2)   // 130 (halo for kw=1,2)

typedef __attribute__((ext_vector_type(8))) short bf16x8;   // 8 bf16 = 4 VGPRs
typedef __attribute__((ext_vector_type(4))) float f32x4;

__device__ __forceinline__ unsigned short bf16_rne(float f) {
    unsigned u = __float_as_uint(f);
    u += 0x7fffu + ((u >> 16) & 1u);          // round-to-nearest-even
    return (unsigned short)(u >> 16);
}
__device__ __forceinline__ float bf16_to_f32(unsigned short h) {
    return __uint_as_float(((unsigned)h) << 16);
}

// ---- prekernel: pack w into per-lane MFMA A-fragments, bf16 hi/lo split.
// Layout: wtf[((kw*2+cot)*64 + lane)*16 + j] = hi, ... + 8 + j = lo
// where A[m=lane&15][k=(lane>>4)*8+j] = w[co=cot*16+m][ci=k][kw]   (12 KB total)
__global__ void prep_w(const float* __restrict__ w, unsigned short* __restrict__ wtf) {
    const int i = blockIdx.x * 256 + threadIdx.x;     // 0..3071
    if (i >= 6 * 64 * 8) return;
    const int f    = i >> 9;          // kw*2+cot
    const int rr   = i & 511;
    const int lane = rr >> 3;
    const int j    = rr & 7;
    const int kw   = f >> 1;
    const int cot  = f & 1;
    const int co   = cot * 16 + (lane & 15);
    const int ci   = (lane >> 4) * 8 + j;
    const float v  = w[(co * C_IN + ci) * KW + kw];
    const unsigned short hi = bf16_rne(v);
    const unsigned short lo = bf16_rne(v - bf16_to_f32(hi));
    wtf[(f * 64 + lane) * 16 + j]     = hi;
    wtf[(f * 64 + lane) * 16 + 8 + j] = lo;
}

__global__ __launch_bounds__(256, 4) void conv1d_mfma(
    const float* __restrict__ x, const unsigned short* __restrict__ wtf,
    float* __restrict__ out)
{
    // transposed tile: xs[l][ci], hi and lo bf16 planes. 2 x 10.4 KB.
    __shared__ __attribute__((aligned(16))) unsigned short xh[XROWS * PITCH];
    __shared__ __attribute__((aligned(16))) unsigned short xl[XROWS * PITCH];

    const int tid  = threadIdx.x;
    const int lane = tid & 63;
    const int wv   = tid >> 6;                 // wave id 0..3
    const int bb   = blockIdx.x >> 8;          // batch
    const int tile = blockIdx.x & (NTILES - 1);
    const int l0   = tile * TILE_L;

    const float* xb = x + ((size_t)bb * C_IN) * L_IN + l0;

    // ---- A fragments: 12 x dwordx4 from L2-hot wtf; issued early, latency
    // hides under the staging phase. 48 VGPRs held for the whole kernel.
    bf16x8 wah[6], wal[6];
#pragma unroll
    for (int f = 0; f < 6; ++f) {
        const bf16x8* p = (const bf16x8*)(wtf + (f * 64 + lane) * 16);
        wah[f] = p[0];
        wal[f] = p[1];
    }

    // ---- stage x tile transposed with bf16 hi/lo split.
    // dword (not float4) global loads so LDS-write lane stride is 1 row
    // (80 B -> 4-way worst-case bank aliasing instead of 16-way).
    {
        const int c    = tid & 31;             // l within 32-chunk
        const int rrow = tid >> 5;             // 0..7
#pragma unroll
        for (int r = 0; r < 4; ++r) {
            const int ci = rrow + r * 8;
            const float* src = xb + (size_t)ci * L_IN;
#pragma unroll
            for (int q = 0; q < 4; ++q) {
                const int l = c + q * 32;
                const float v = src[l];        // l0+127 <= 32767: always in bounds
                const unsigned short hi = bf16_rne(v);
                const unsigned short lo = bf16_rne(v - bf16_to_f32(hi));
                xh[l * PITCH + ci] = hi;
                xl[l * PITCH + ci] = lo;
            }
        }
    }
    // halo cols 128,129 (OOB only for tile 255 -> zeros; those feed only
    // the two invalid output columns anyway)
    if (tid < 64) {
        const int h  = tid & 1;
        const int ci = tid >> 1;
        const int gl = l0 + TILE_L + h;
        float v = 0.f;
        if (gl < L_IN) v = xb[(size_t)ci * L_IN + TILE_L + h];
        const unsigned short hi = bf16_rne(v);
        const unsigned short lo = bf16_rne(v - bf16_to_f32(hi));
        xh[(TILE_L + h) * PITCH + ci] = hi;
        xl[(TILE_L + h) * PITCH + ci] = lo;
    }
    __syncthreads();

    // ---- MFMA: conv as 3 shifted GEMMs, K = C_IN = 32 per mfma.
    // 3-term f32 emulation: wh*xh + wh*xl + wl*xh  (drops only lo*lo ~ 2^-18)
    const int n  = lane & 15;                  // B col / D col  (l offset)
    const int kg = lane >> 4;                  // k-group (ci block of 8)
    const int lb = wv * 32;                    // wave's l window in tile

    f32x4 acc[2][2] = {{{0.f,0.f,0.f,0.f},{0.f,0.f,0.f,0.f}},
                       {{0.f,0.f,0.f,0.f},{0.f,0.f,0.f,0.f}}};

#pragma unroll
    for (int kw = 0; kw < KW; ++kw) {
#pragma unroll
        for (int lt = 0; lt < 2; ++lt) {
            const int lrow = lb + lt * 16 + n + kw;       // <= 129
            const bf16x8 bh = *(const bf16x8*)&xh[lrow * PITCH + kg * 8];
            const bf16x8 bl = *(const bf16x8*)&xl[lrow * PITCH + kg * 8];
#pragma unroll
            for (int cot = 0; cot < 2; ++cot) {
                const int f = kw * 2 + cot;
                acc[cot][lt] = __builtin_amdgcn_mfma_f32_16x16x32_bf16(wah[f], bh, acc[cot][lt], 0, 0, 0);
                acc[cot][lt] = __builtin_amdgcn_mfma_f32_16x16x32_bf16(wah[f], bl, acc[cot][lt], 0, 0, 0);
                acc[cot][lt] = __builtin_amdgcn_mfma_f32_16x16x32_bf16(wal[f], bh, acc[cot][lt], 0, 0, 0);
            }
        }
    }

    // ---- store: D layout col=lane&15 (l), row=(lane>>4)*4+r (co).
    // Each store: 4 co-rows x 16 l x 4 B = 4 aligned 64 B cachelines.
    float* ob = out + (size_t)bb * C_OUT * L_OUT;
    const int lw = l0 + lb;
#pragma unroll
    for (int cot = 0; cot < 2; ++cot) {
#pragma unroll
        for (int lt = 0; lt < 2; ++lt) {
            const int l = lw + lt * 16 + n;
            if (l < L_OUT) {                   // only trims 2 lanes in last tile
                float* op = ob + (size_t)(cot * 16 + kg * 4) * L_OUT + l;
#pragma unroll
                for (int r = 0; r < 4; ++r)
                    op[(size_t)r * L_OUT] = acc[cot][lt][r];
            }
        }
    }
}

extern "C" void kernel_launch(void* const* d_in, const int* in_sizes, int n_in,
                              void* d_out, int out_size, void* d_ws, size_t ws_size,
                              hipStream_t stream) {
    const float* x = (const float*)d_in[0];
    const float* w = (const float*)d_in[1];
    float* out     = (float*)d_out;
    unsigned short* wtf = (unsigned short*)d_ws;   // 6144 ushorts = 12 KB scratch

    prep_w<<<dim3(12), 256, 0, stream>>>(w, wtf);
    conv1d_mfma<<<dim3(16 * NTILES), 256, 0, stream>>>(x, wtf, out);
}